// Round 1
// baseline (5426.810 us; speedup 1.0000x reference)
//
#include <hip/hip_runtime.h>
#include <math.h>

#define NIx 32
#define NOx 2
#define NUx 10
#define NHx 1024
#define NBx 16384
#define MIx 138
#define EPSQ 1e-4f
#define BNEPS 1e-5f
#define ITERS 30
#define SLOPE 0.2f
#define SIGMA_C 0.1f

// workspace layout (float offsets)
#define QM_OFF 0       // 10 rows x 12 (padded)
#define G_OFF 128      // 144 rows x 12 (padded, zero pad rows/cols)
#define H_OFF 1856     // 144
#define A1_OFF 2048    // 1024
#define C1_OFF 3072    // 1024
#define B2P_OFF 4096   // 10 (pad to 4112)
#define S1_OFF 4112    // 1024
#define SQ1_OFF 5136   // 1024
#define S2_OFF 6160    // 10 (pad 16)
#define SQ2_OFF 6176   // 10 (pad to 6208)
#define PRAW_OFF 6208  // 16384*10
#define ZERO_LEN (6208 - S1_OFF)

__device__ __forceinline__ float frcp(float x){ return __builtin_amdgcn_rcpf(x); }
__device__ __forceinline__ float frsq(float x){ return __builtin_amdgcn_rsqf(x); }
__device__ __forceinline__ float lrelu(float x){ return x > 0.0f ? x : SLOPE * x; }

__global__ __launch_bounds__(256) void k_zero(float* ws){
    int i = blockIdx.x * 256 + threadIdx.x;
    if (i < ZERO_LEN) ws[S1_OFF + i] = 0.0f;
}

// ---------- build Q_hat, G, h (one block) ----------
__global__ __launch_bounds__(256) void k_build(const float* L, const float* LP, const float* LR,
                                               const float* A, const float* Bm,
                                               const float* u0, const float* s0, float* ws){
    __shared__ float sL[1024], sLP[1024], sA[1024], sQ[1024], sP[1024];
    __shared__ float sPow[4][64];   // [power][i*2+c]
    __shared__ float sBh[128*10];
    __shared__ float sQB[128*10];
    __shared__ float sR[3];
    int t = threadIdx.x;
    for (int idx = t; idx < 1024; idx += 256){
        int i = idx >> 5, j = idx & 31;
        sL[idx]  = (j <= i) ? L[idx]  : 0.0f;
        sLP[idx] = (j <= i) ? LP[idx] : 0.0f;
        sA[idx]  = A[idx];
    }
    if (t < 64) sPow[0][t] = Bm[t];
    if (t == 0){
        float a = LR[0], b = LR[2], c = LR[3];   // tril: [[a,0],[b,c]]
        sR[0] = a*a + EPSQ; sR[1] = a*b; sR[2] = b*b + c*c + EPSQ;
    }
    __syncthreads();
    for (int idx = t; idx < 1024; idx += 256){
        int i = idx >> 5, j = idx & 31;
        float q = 0.0f, p = 0.0f;
        for (int k = 0; k < 32; ++k){
            q = fmaf(sL[i*32+k],  sL[j*32+k],  q);
            p = fmaf(sLP[i*32+k], sLP[j*32+k], p);
        }
        if (i == j){ q += EPSQ; p += EPSQ; }
        sQ[idx] = q; sP[idx] = p;
    }
    for (int kp = 1; kp < 4; ++kp){
        __syncthreads();
        if (t < 64){
            int i = t >> 1, c = t & 1;
            float a = 0.0f;
            for (int j = 0; j < 32; ++j) a = fmaf(sA[i*32+j], sPow[kp-1][j*2+c], a);
            sPow[kp][t] = a;
        }
    }
    __syncthreads();
    for (int idx = t; idx < 1280; idx += 256){
        int r = idx / 10, c = idx % 10;
        int bi = r >> 5, ri = r & 31, bj = c >> 1, cj = c & 1;
        sBh[idx] = (bj <= bi) ? sPow[bi-bj][ri*2+cj] : 0.0f;
    }
    __syncthreads();
    for (int idx = t; idx < 1280; idx += 256){
        int r = idx / 10, c = idx % 10;
        int bi = r >> 5, ri = r & 31;
        const float* Qd = (bi < 3) ? sQ : sP;
        float a = 0.0f;
        for (int k = 0; k < 32; ++k) a = fmaf(Qd[ri*32+k], sBh[(bi*32+k)*10+c], a);
        sQB[idx] = a;
    }
    __syncthreads();
    if (t < 120){
        int i = t / 12, j = t % 12;
        float a = 0.0f;
        if (j < 10){
            for (int r = 0; r < 128; ++r) a = fmaf(sBh[r*10+i], sQB[r*10+j], a);
            if ((i >> 1) == (j >> 1)) a += sR[(i&1)+(j&1)];
        }
        ws[QM_OFF + t] = a;
    }
    for (int idx = t; idx < 144*12; idx += 256){
        int m = idx / 12, i = idx % 12;
        float v = 0.0f;
        if (i < 10 && m < MIx) v = (m < 10) ? ((i == m) ? 1.0f : 0.0f) : sBh[(m-10)*10 + i];
        ws[G_OFF + idx] = v;
    }
    for (int m = t; m < 144; m += 256){
        float hv = 0.0f;
        if (m < MIx){
            hv = s0[m];
            if (m < 10) hv += u0[m];
            else { for (int i = 0; i < 10; ++i) hv = fmaf(sBh[(m-10)*10+i], u0[i], hv); }
        }
        ws[H_OFF + m] = hv;
    }
}

// ---------- BN1 stats: h1 = lrelu(x@W1^T + b1), accumulate per-col sum/sumsq ----------
__global__ __launch_bounds__(256) void k_stats1(const float* x, const float* w1, const float* b1, float* ws){
    __shared__ float xs[256*32];
    int t = threadIdx.x;
    int rb = blockIdx.x >> 2;
    int cb = blockIdx.x & 3;
    int r0 = rb * 256;
    int c = cb * 256 + t;
    const float4* xg4 = (const float4*)(x + (size_t)r0 * 32);
    float4* xs4 = (float4*)xs;
    for (int i = t; i < 2048; i += 256) xs4[i] = xg4[i];
    const float4* wg4 = (const float4*)(w1 + (size_t)c * 32);
    float4 wr[8];
    #pragma unroll
    for (int q = 0; q < 8; ++q) wr[q] = wg4[q];
    float bc = b1[c];
    __syncthreads();
    const float4* xr4 = (const float4*)xs;
    float sum = 0.0f, sq = 0.0f;
    for (int r = 0; r < 256; ++r){
        float a0 = 0, a1 = 0, a2 = 0, a3 = 0;
        #pragma unroll
        for (int q = 0; q < 8; ++q){
            float4 v = xr4[r*8 + q];
            a0 = fmaf(v.x, wr[q].x, a0);
            a1 = fmaf(v.y, wr[q].y, a1);
            a2 = fmaf(v.z, wr[q].z, a2);
            a3 = fmaf(v.w, wr[q].w, a3);
        }
        float h = lrelu((a0 + a1) + (a2 + a3) + bc);
        sum += h; sq = fmaf(h, h, sq);
    }
    atomicAdd(&ws[S1_OFF + c], sum);
    atomicAdd(&ws[SQ1_OFF + c], sq);
}

// ---------- finalize BN1 affine + fold into fc2 bias ----------
__global__ __launch_bounds__(256) void k_fin1(const float* g1, const float* bb1,
                                              const float* w2, const float* b2, float* ws){
    int t = threadIdx.x;
    for (int k = t; k < 1024; k += 256){
        float mu  = ws[S1_OFF + k] * (1.0f/16384.0f);
        float var = ws[SQ1_OFF + k] * (1.0f/16384.0f) - mu*mu;
        float a1 = g1[k] / sqrtf(var + BNEPS);
        ws[A1_OFF + k] = a1;
        ws[C1_OFF + k] = bb1[k] - mu * a1;
    }
    __syncthreads();
    if (t < 10){
        float a = b2[t];
        for (int k = 0; k < 1024; ++k) a = fmaf(ws[C1_OFF + k], w2[t*1024 + k], a);
        ws[B2P_OFF + t] = a;
    }
}

// ---------- fc2: p_raw = lrelu((h1*a1)@W2^T + b2'), + BN2 stats ----------
__global__ __launch_bounds__(256) void k_fc2(const float* x, const float* w1, const float* b1,
                                             const float* w2, float* ws){
    __shared__ float ws1[128*32];     // W1 chunk [kl][c]
    __shared__ float w2t[128*12];     // W2 chunk transposed, padded to 12
    __shared__ float sab[128*2];      // (a1, b1) per kl
    int t = threadIdx.x;
    int r0 = blockIdx.x * 64;
    int r = t & 63;
    int q = t >> 6;                   // wave id: k-quarter
    const float4* xg4 = (const float4*)(x + (size_t)(r0 + r) * 32);
    float4 xr[8];
    #pragma unroll
    for (int i = 0; i < 8; ++i) xr[i] = xg4[i];
    float acc[10];
    #pragma unroll
    for (int j = 0; j < 10; ++j) acc[j] = 0.0f;

    for (int kc = 0; kc < 1024; kc += 128){
        __syncthreads();
        const float4* w1g = (const float4*)(w1 + (size_t)kc * 32);
        float4* ws14 = (float4*)ws1;
        for (int i = t; i < 1024; i += 256) ws14[i] = w1g[i];
        for (int i = t; i < 1280; i += 256){
            int kl = i & 127, j = i >> 7;
            w2t[kl*12 + j] = w2[j*1024 + kc + kl];
        }
        if (t < 256){ int kl = t >> 1, j = 10 + (t & 1); w2t[kl*12 + j] = 0.0f; }
        if (t < 128){ sab[t*2] = ws[A1_OFF + kc + t]; sab[t*2+1] = b1[kc + t]; }
        __syncthreads();
        const float4* w1r = (const float4*)ws1;
        const float4* w2r = (const float4*)w2t;
        const float2* abr = (const float2*)sab;
        #pragma unroll 4
        for (int kk = 0; kk < 32; ++kk){
            int kl = q*32 + kk;
            float a0 = 0, a1 = 0, a2 = 0, a3 = 0;
            #pragma unroll
            for (int qq = 0; qq < 8; ++qq){
                float4 wv = w1r[kl*8 + qq];
                float4 xv = xr[qq];
                a0 = fmaf(xv.x, wv.x, a0);
                a1 = fmaf(xv.y, wv.y, a1);
                a2 = fmaf(xv.z, wv.z, a2);
                a3 = fmaf(xv.w, wv.w, a3);
            }
            float2 ab = abr[kl];
            float h = lrelu((a0 + a1) + (a2 + a3) + ab.y) * ab.x;
            float4 wa = w2r[kl*3+0], wb = w2r[kl*3+1], wc = w2r[kl*3+2];
            acc[0] = fmaf(h, wa.x, acc[0]); acc[1] = fmaf(h, wa.y, acc[1]);
            acc[2] = fmaf(h, wa.z, acc[2]); acc[3] = fmaf(h, wa.w, acc[3]);
            acc[4] = fmaf(h, wb.x, acc[4]); acc[5] = fmaf(h, wb.y, acc[5]);
            acc[6] = fmaf(h, wb.z, acc[6]); acc[7] = fmaf(h, wb.w, acc[7]);
            acc[8] = fmaf(h, wc.x, acc[8]); acc[9] = fmaf(h, wc.y, acc[9]);
        }
    }
    __syncthreads();
    float* pacc = ws1;   // reuse LDS
    #pragma unroll
    for (int j = 0; j < 10; ++j) pacc[(q*64 + r)*10 + j] = acc[j];
    __syncthreads();
    if (t < 64){
        float pv[10];
        #pragma unroll
        for (int j = 0; j < 10; ++j){
            float a = ws[B2P_OFF + j];
            a += pacc[t*10+j] + pacc[(64+t)*10+j] + pacc[(128+t)*10+j] + pacc[(192+t)*10+j];
            pv[j] = lrelu(a);
        }
        #pragma unroll
        for (int j = 0; j < 10; ++j) ws[PRAW_OFF + (size_t)(r0 + t)*10 + j] = pv[j];
        float sv[10], qv[10];
        #pragma unroll
        for (int j = 0; j < 10; ++j){ sv[j] = pv[j]; qv[j] = pv[j]*pv[j]; }
        #pragma unroll
        for (int m = 1; m < 64; m <<= 1){
            #pragma unroll
            for (int j = 0; j < 10; ++j){
                sv[j] += __shfl_xor(sv[j], m);
                qv[j] += __shfl_xor(qv[j], m);
            }
        }
        if (t == 0){
            #pragma unroll
            for (int j = 0; j < 10; ++j){
                atomicAdd(&ws[S2_OFF + j], sv[j]);
                atomicAdd(&ws[SQ2_OFF + j], qv[j]);
            }
        }
    }
}

// ---------- batched IPM: 8 lanes per element, 18 constraints per lane ----------
#define TIX(i,j) ((i)*((i)+1)/2 + (j))
#define LOADG(kk) \
    float4 ga_ = gptr[(kk)*3+0]; float4 gb_ = gptr[(kk)*3+1]; float4 gc_ = gptr[(kk)*3+2]; \
    float g[10] = {ga_.x, ga_.y, ga_.z, ga_.w, gb_.x, gb_.y, gb_.z, gb_.w, gc_.x, gc_.y};

__global__ __launch_bounds__(256) void k_ipm(const float* ws, const float* g2, const float* bb2, float* out){
    __shared__ float sG[144*12];
    __shared__ float sh[144];
    __shared__ float sQm[120];
    __shared__ float sa2[10], sc2[10];
    int t = threadIdx.x;
    for (int i = t; i < 1728; i += 256) sG[i] = ws[G_OFF + i];
    for (int i = t; i < 144; i += 256)  sh[i] = ws[H_OFF + i];
    if (t < 120) sQm[t] = ws[QM_OFF + t];
    if (t < 10){
        float mu  = ws[S2_OFF + t] * (1.0f/16384.0f);
        float var = ws[SQ2_OFF + t] * (1.0f/16384.0f) - mu*mu;
        float a2 = g2[t] / sqrtf(var + BNEPS);
        sa2[t] = a2; sc2[t] = bb2[t] - mu * a2;
    }
    __syncthreads();

    int lg = t & 7;
    int elem = blockIdx.x * 32 + (t >> 3);
    int m0 = lg * 18;
    const float2* p2 = (const float2*)(ws + PRAW_OFF + (size_t)elem * 10);
    float pv[10];
    #pragma unroll
    for (int i = 0; i < 5; ++i){
        float2 v = p2[i];
        pv[2*i]   = fmaf(v.x, sa2[2*i],   sc2[2*i]);
        pv[2*i+1] = fmaf(v.y, sa2[2*i+1], sc2[2*i+1]);
    }
    float z[10];
    #pragma unroll
    for (int i = 0; i < 10; ++i) z[i] = 0.0f;
    float s[18], lam[18], rp[18], ds[18];
    #pragma unroll
    for (int k = 0; k < 18; ++k){ s[k] = 1.0f; lam[k] = (m0 + k < MIx) ? 1.0f : 0.0f; }
    const float4* gptr = (const float4*)(sG + m0 * 12);

    #pragma unroll 1
    for (int it = 0; it < ITERS; ++it){
        float lamG[10], Hm[55], sl = 0.0f;
        #pragma unroll
        for (int i = 0; i < 10; ++i) lamG[i] = 0.0f;
        #pragma unroll
        for (int i = 0; i < 55; ++i) Hm[i] = 0.0f;
        // ---- loop A: lam@G, rp, mu partial, H partial
        #pragma unroll
        for (int k = 0; k < 18; ++k){
            LOADG(k);
            float sk = s[k], lk = lam[k];
            #pragma unroll
            for (int i = 0; i < 10; ++i) lamG[i] = fmaf(lk, g[i], lamG[i]);
            float r = sk - sh[m0 + k];
            #pragma unroll
            for (int i = 0; i < 10; ++i) r = fmaf(z[i], g[i], r);
            rp[k] = r;
            sl = fmaf(sk, lk, sl);
            float w = lk * frcp(sk);
            float wg[10];
            #pragma unroll
            for (int i = 0; i < 10; ++i) wg[i] = w * g[i];
            #pragma unroll
            for (int i = 0; i < 10; ++i){
                #pragma unroll
                for (int j = 0; j <= i; ++j) Hm[TIX(i,j)] = fmaf(wg[i], g[j], Hm[TIX(i,j)]);
            }
        }
        // ---- butterfly reductions over the 8-lane group
        #pragma unroll
        for (int m = 1; m < 8; m <<= 1){
            #pragma unroll
            for (int i = 0; i < 10; ++i) lamG[i] += __shfl_xor(lamG[i], m);
            sl += __shfl_xor(sl, m);
            #pragma unroll
            for (int i = 0; i < 55; ++i) Hm[i] += __shfl_xor(Hm[i], m);
        }
        float smu = SIGMA_C * sl * (1.0f/138.0f);
        // rd = z@Qm + p + lam@G
        float rd[10];
        #pragma unroll
        for (int i = 0; i < 10; ++i) rd[i] = pv[i] + lamG[i];
        #pragma unroll
        for (int j = 0; j < 10; ++j){
            float zj = z[j];
            #pragma unroll
            for (int i = 0; i < 10; ++i) rd[i] = fmaf(zj, sQm[j*12 + i], rd[i]);
        }
        // H += Qm
        #pragma unroll
        for (int i = 0; i < 10; ++i){
            #pragma unroll
            for (int j = 0; j <= i; ++j) Hm[TIX(i,j)] += sQm[i*12 + j];
        }
        // ---- loop B: rhs accumulation
        float racc[10];
        #pragma unroll
        for (int i = 0; i < 10; ++i) racc[i] = 0.0f;
        #pragma unroll
        for (int k = 0; k < 18; ++k){
            LOADG(k);
            float sk = s[k], lk = lam[k];
            float isk = frcp(sk);
            float rc = fmaf(sk, lk, -smu);
            float coef = isk * fmaf(lk, rp[k], -rc);
            #pragma unroll
            for (int i = 0; i < 10; ++i) racc[i] = fmaf(coef, g[i], racc[i]);
        }
        #pragma unroll
        for (int m = 1; m < 8; m <<= 1){
            #pragma unroll
            for (int i = 0; i < 10; ++i) racc[i] += __shfl_xor(racc[i], m);
        }
        float rhs[10];
        #pragma unroll
        for (int i = 0; i < 10; ++i) rhs[i] = -(rd[i] + racc[i]);
        // ---- Cholesky (reciprocal diag stored in place)
        #pragma unroll
        for (int j = 0; j < 10; ++j){
            float d = Hm[TIX(j,j)];
            #pragma unroll
            for (int k2 = 0; k2 < j; ++k2){ float v = Hm[TIX(j,k2)]; d = fmaf(-v, v, d); }
            d = fmaxf(d, 1e-30f);
            float rinv = frsq(d);
            Hm[TIX(j,j)] = rinv;
            #pragma unroll
            for (int i = j+1; i < 10; ++i){
                float v2 = Hm[TIX(i,j)];
                #pragma unroll
                for (int k2 = 0; k2 < j; ++k2) v2 = fmaf(-Hm[TIX(i,k2)], Hm[TIX(j,k2)], v2);
                Hm[TIX(i,j)] = v2 * rinv;
            }
        }
        // forward/back solve
        #pragma unroll
        for (int i = 0; i < 10; ++i){
            float v2 = rhs[i];
            #pragma unroll
            for (int k2 = 0; k2 < i; ++k2) v2 = fmaf(-Hm[TIX(i,k2)], rhs[k2], v2);
            rhs[i] = v2 * Hm[TIX(i,i)];
        }
        float dz[10];
        #pragma unroll
        for (int i = 9; i >= 0; --i){
            float v2 = rhs[i];
            #pragma unroll
            for (int k2 = i+1; k2 < 10; ++k2) v2 = fmaf(-Hm[TIX(k2,i)], dz[k2], v2);
            dz[i] = v2 * Hm[TIX(i,i)];
        }
        // ---- loop C: ds, step-length candidates
        float amin = 3.0e38f;
        #pragma unroll
        for (int k = 0; k < 18; ++k){
            LOADG(k);
            float dot = 0.0f;
            #pragma unroll
            for (int i = 0; i < 10; ++i) dot = fmaf(dz[i], g[i], dot);
            float dsk = -rp[k] - dot;
            bool val = (m0 + k) < MIx;
            dsk = val ? dsk : 0.0f;
            ds[k] = dsk;
            float sk = s[k], lk = lam[k];
            float isk = frcp(sk);
            float rc = fmaf(sk, lk, -smu);
            float dlk = -(rc + lk * dsk) * isk;
            dlk = val ? dlk : 0.0f;
            float r1 = (dsk < 0.0f) ? sk * frcp(-dsk) : 3.0e38f;
            float r2 = (dlk < 0.0f) ? lk * frcp(-dlk) : 3.0e38f;
            amin = fminf(amin, fminf(r1, r2));
        }
        #pragma unroll
        for (int m = 1; m < 8; m <<= 1) amin = fminf(amin, __shfl_xor(amin, m));
        float alpha = fminf(1.0f, 0.99f * amin);
        // ---- updates
        #pragma unroll
        for (int i = 0; i < 10; ++i) z[i] = fmaf(alpha, dz[i], z[i]);
        #pragma unroll
        for (int k = 0; k < 18; ++k){
            float sk = s[k], lk = lam[k], dsk = ds[k];
            float isk = frcp(sk);
            float rc = fmaf(sk, lk, -smu);
            float dlk = -(rc + lk * dsk) * isk;
            dlk = ((m0 + k) < MIx) ? dlk : 0.0f;
            s[k]   = fmaf(alpha, dsk, sk);
            lam[k] = fmaf(alpha, dlk, lk);
        }
    }
    if (lg == 0) out[elem] = z[0];
}

extern "C" void kernel_launch(void* const* d_in, const int* in_sizes, int n_in,
                              void* d_out, int out_size, void* d_ws, size_t ws_size,
                              hipStream_t stream){
    const float* x   = (const float*)d_in[0];
    const float* w1  = (const float*)d_in[1];
    const float* b1  = (const float*)d_in[2];
    const float* w2  = (const float*)d_in[3];
    const float* b2  = (const float*)d_in[4];
    const float* g1  = (const float*)d_in[5];
    const float* bb1 = (const float*)d_in[6];
    const float* g2  = (const float*)d_in[7];
    const float* bb2 = (const float*)d_in[8];
    const float* L   = (const float*)d_in[9];
    const float* LP  = (const float*)d_in[10];
    const float* LR  = (const float*)d_in[11];
    const float* A   = (const float*)d_in[12];
    const float* Bm  = (const float*)d_in[13];
    const float* u0  = (const float*)d_in[14];
    const float* s0  = (const float*)d_in[15];
    float* ws  = (float*)d_ws;
    float* out = (float*)d_out;

    hipLaunchKernelGGL(k_zero,   dim3((ZERO_LEN + 255)/256), dim3(256), 0, stream, ws);
    hipLaunchKernelGGL(k_build,  dim3(1),   dim3(256), 0, stream, L, LP, LR, A, Bm, u0, s0, ws);
    hipLaunchKernelGGL(k_stats1, dim3(256), dim3(256), 0, stream, x, w1, b1, ws);
    hipLaunchKernelGGL(k_fin1,   dim3(1),   dim3(256), 0, stream, g1, bb1, w2, b2, ws);
    hipLaunchKernelGGL(k_fc2,    dim3(256), dim3(256), 0, stream, x, w1, b1, w2, ws);
    hipLaunchKernelGGL(k_ipm,    dim3(512), dim3(256), 0, stream, ws, g2, bb2, out);
}

// Round 2
// 1952.372 us; speedup vs baseline: 2.7796x; 2.7796x over previous
//
#include <hip/hip_runtime.h>
#include <math.h>

#define NIx 32
#define NOx 2
#define NUx 10
#define NHx 1024
#define NBx 16384
#define MIx 138
#define EPSQ 1e-4f
#define BNEPS 1e-5f
#define ITERS 30
#define SLOPE 0.2f
#define SIGMA_C 0.1f

// workspace layout (float offsets)
#define QM_OFF 0       // 10 rows x 12 (padded)
#define G_OFF 128      // 144 rows x 12 (padded, zero pad rows/cols)
#define H_OFF 1856     // 144
#define A1_OFF 2048    // 1024
#define C1_OFF 3072    // 1024
#define B2P_OFF 4096   // 10 (pad to 4112)
#define S1_OFF 4112    // 1024
#define SQ1_OFF 5136   // 1024
#define S2_OFF 6160    // 10 (pad 16)
#define SQ2_OFF 6176   // 10 (pad to 6208)
#define PRAW_OFF 6208  // 16384*10
#define ZERO_LEN (6208 - S1_OFF)

__device__ __forceinline__ float frcp(float x){ return __builtin_amdgcn_rcpf(x); }
__device__ __forceinline__ float frsq(float x){ return __builtin_amdgcn_rsqf(x); }
__device__ __forceinline__ float lrelu(float x){ return x > 0.0f ? x : SLOPE * x; }

__global__ __launch_bounds__(256) void k_zero(float* ws){
    int i = blockIdx.x * 256 + threadIdx.x;
    if (i < ZERO_LEN) ws[S1_OFF + i] = 0.0f;
}

// ---------- build Q_hat, G, h (one block) ----------
__global__ __launch_bounds__(256) void k_build(const float* L, const float* LP, const float* LR,
                                               const float* A, const float* Bm,
                                               const float* u0, const float* s0, float* ws){
    __shared__ float sL[1024], sLP[1024], sA[1024], sQ[1024], sP[1024];
    __shared__ float sPow[4][64];   // [power][i*2+c]
    __shared__ float sBh[128*10];
    __shared__ float sQB[128*10];
    __shared__ float sR[3];
    int t = threadIdx.x;
    for (int idx = t; idx < 1024; idx += 256){
        int i = idx >> 5, j = idx & 31;
        sL[idx]  = (j <= i) ? L[idx]  : 0.0f;
        sLP[idx] = (j <= i) ? LP[idx] : 0.0f;
        sA[idx]  = A[idx];
    }
    if (t < 64) sPow[0][t] = Bm[t];
    if (t == 0){
        float a = LR[0], b = LR[2], c = LR[3];   // tril: [[a,0],[b,c]]
        sR[0] = a*a + EPSQ; sR[1] = a*b; sR[2] = b*b + c*c + EPSQ;
    }
    __syncthreads();
    for (int idx = t; idx < 1024; idx += 256){
        int i = idx >> 5, j = idx & 31;
        float q = 0.0f, p = 0.0f;
        for (int k = 0; k < 32; ++k){
            q = fmaf(sL[i*32+k],  sL[j*32+k],  q);
            p = fmaf(sLP[i*32+k], sLP[j*32+k], p);
        }
        if (i == j){ q += EPSQ; p += EPSQ; }
        sQ[idx] = q; sP[idx] = p;
    }
    for (int kp = 1; kp < 4; ++kp){
        __syncthreads();
        if (t < 64){
            int i = t >> 1, c = t & 1;
            float a = 0.0f;
            for (int j = 0; j < 32; ++j) a = fmaf(sA[i*32+j], sPow[kp-1][j*2+c], a);
            sPow[kp][t] = a;
        }
    }
    __syncthreads();
    for (int idx = t; idx < 1280; idx += 256){
        int r = idx / 10, c = idx % 10;
        int bi = r >> 5, ri = r & 31, bj = c >> 1, cj = c & 1;
        sBh[idx] = (bj <= bi) ? sPow[bi-bj][ri*2+cj] : 0.0f;
    }
    __syncthreads();
    for (int idx = t; idx < 1280; idx += 256){
        int r = idx / 10, c = idx % 10;
        int bi = r >> 5, ri = r & 31;
        const float* Qd = (bi < 3) ? sQ : sP;
        float a = 0.0f;
        for (int k = 0; k < 32; ++k) a = fmaf(Qd[ri*32+k], sBh[(bi*32+k)*10+c], a);
        sQB[idx] = a;
    }
    __syncthreads();
    if (t < 120){
        int i = t / 12, j = t % 12;
        float a = 0.0f;
        if (j < 10){
            for (int r = 0; r < 128; ++r) a = fmaf(sBh[r*10+i], sQB[r*10+j], a);
            if ((i >> 1) == (j >> 1)) a += sR[(i&1)+(j&1)];
        }
        ws[QM_OFF + t] = a;
    }
    for (int idx = t; idx < 144*12; idx += 256){
        int m = idx / 12, i = idx % 12;
        float v = 0.0f;
        if (i < 10 && m < MIx) v = (m < 10) ? ((i == m) ? 1.0f : 0.0f) : sBh[(m-10)*10 + i];
        ws[G_OFF + idx] = v;
    }
    for (int m = t; m < 144; m += 256){
        float hv = 0.0f;
        if (m < MIx){
            hv = s0[m];
            if (m < 10) hv += u0[m];
            else { for (int i = 0; i < 10; ++i) hv = fmaf(sBh[(m-10)*10+i], u0[i], hv); }
        }
        ws[H_OFF + m] = hv;
    }
}

// ---------- BN1 stats: h1 = lrelu(x@W1^T + b1), accumulate per-col sum/sumsq ----------
__global__ __launch_bounds__(256) void k_stats1(const float* x, const float* w1, const float* b1, float* ws){
    __shared__ float xs[256*32];
    int t = threadIdx.x;
    int rb = blockIdx.x >> 2;
    int cb = blockIdx.x & 3;
    int r0 = rb * 256;
    int c = cb * 256 + t;
    const float4* xg4 = (const float4*)(x + (size_t)r0 * 32);
    float4* xs4 = (float4*)xs;
    for (int i = t; i < 2048; i += 256) xs4[i] = xg4[i];
    const float4* wg4 = (const float4*)(w1 + (size_t)c * 32);
    float4 wr[8];
    #pragma unroll
    for (int q = 0; q < 8; ++q) wr[q] = wg4[q];
    float bc = b1[c];
    __syncthreads();
    const float4* xr4 = (const float4*)xs;
    float sum = 0.0f, sq = 0.0f;
    for (int r = 0; r < 256; ++r){
        float a0 = 0, a1 = 0, a2 = 0, a3 = 0;
        #pragma unroll
        for (int q = 0; q < 8; ++q){
            float4 v = xr4[r*8 + q];
            a0 = fmaf(v.x, wr[q].x, a0);
            a1 = fmaf(v.y, wr[q].y, a1);
            a2 = fmaf(v.z, wr[q].z, a2);
            a3 = fmaf(v.w, wr[q].w, a3);
        }
        float h = lrelu((a0 + a1) + (a2 + a3) + bc);
        sum += h; sq = fmaf(h, h, sq);
    }
    atomicAdd(&ws[S1_OFF + c], sum);
    atomicAdd(&ws[SQ1_OFF + c], sq);
}

// ---------- finalize BN1 affine + fold into fc2 bias ----------
__global__ __launch_bounds__(256) void k_fin1(const float* g1, const float* bb1,
                                              const float* w2, const float* b2, float* ws){
    int t = threadIdx.x;
    for (int k = t; k < 1024; k += 256){
        float mu  = ws[S1_OFF + k] * (1.0f/16384.0f);
        float var = ws[SQ1_OFF + k] * (1.0f/16384.0f) - mu*mu;
        float a1 = g1[k] / sqrtf(var + BNEPS);
        ws[A1_OFF + k] = a1;
        ws[C1_OFF + k] = bb1[k] - mu * a1;
    }
    __syncthreads();
    if (t < 10){
        float a = b2[t];
        for (int k = 0; k < 1024; ++k) a = fmaf(ws[C1_OFF + k], w2[t*1024 + k], a);
        ws[B2P_OFF + t] = a;
    }
}

// ---------- fc2: p_raw = lrelu((h1*a1)@W2^T + b2'), + BN2 stats ----------
__global__ __launch_bounds__(256) void k_fc2(const float* x, const float* w1, const float* b1,
                                             const float* w2, float* ws){
    __shared__ float ws1[128*32];     // W1 chunk [kl][c]
    __shared__ float w2t[128*12];     // W2 chunk transposed, padded to 12
    __shared__ float sab[128*2];      // (a1, b1) per kl
    int t = threadIdx.x;
    int r0 = blockIdx.x * 64;
    int r = t & 63;
    int q = t >> 6;                   // wave id: k-quarter
    const float4* xg4 = (const float4*)(x + (size_t)(r0 + r) * 32);
    float4 xr[8];
    #pragma unroll
    for (int i = 0; i < 8; ++i) xr[i] = xg4[i];
    float acc[10];
    #pragma unroll
    for (int j = 0; j < 10; ++j) acc[j] = 0.0f;

    for (int kc = 0; kc < 1024; kc += 128){
        __syncthreads();
        const float4* w1g = (const float4*)(w1 + (size_t)kc * 32);
        float4* ws14 = (float4*)ws1;
        for (int i = t; i < 1024; i += 256) ws14[i] = w1g[i];
        for (int i = t; i < 1280; i += 256){
            int kl = i & 127, j = i >> 7;
            w2t[kl*12 + j] = w2[j*1024 + kc + kl];
        }
        if (t < 256){ int kl = t >> 1, j = 10 + (t & 1); w2t[kl*12 + j] = 0.0f; }
        if (t < 128){ sab[t*2] = ws[A1_OFF + kc + t]; sab[t*2+1] = b1[kc + t]; }
        __syncthreads();
        const float4* w1r = (const float4*)ws1;
        const float4* w2r = (const float4*)w2t;
        const float2* abr = (const float2*)sab;
        #pragma unroll 4
        for (int kk = 0; kk < 32; ++kk){
            int kl = q*32 + kk;
            float a0 = 0, a1 = 0, a2 = 0, a3 = 0;
            #pragma unroll
            for (int qq = 0; qq < 8; ++qq){
                float4 wv = w1r[kl*8 + qq];
                float4 xv = xr[qq];
                a0 = fmaf(xv.x, wv.x, a0);
                a1 = fmaf(xv.y, wv.y, a1);
                a2 = fmaf(xv.z, wv.z, a2);
                a3 = fmaf(xv.w, wv.w, a3);
            }
            float2 ab = abr[kl];
            float h = lrelu((a0 + a1) + (a2 + a3) + ab.y) * ab.x;
            float4 wa = w2r[kl*3+0], wb = w2r[kl*3+1], wc = w2r[kl*3+2];
            acc[0] = fmaf(h, wa.x, acc[0]); acc[1] = fmaf(h, wa.y, acc[1]);
            acc[2] = fmaf(h, wa.z, acc[2]); acc[3] = fmaf(h, wa.w, acc[3]);
            acc[4] = fmaf(h, wb.x, acc[4]); acc[5] = fmaf(h, wb.y, acc[5]);
            acc[6] = fmaf(h, wb.z, acc[6]); acc[7] = fmaf(h, wb.w, acc[7]);
            acc[8] = fmaf(h, wc.x, acc[8]); acc[9] = fmaf(h, wc.y, acc[9]);
        }
    }
    __syncthreads();
    float* pacc = ws1;   // reuse LDS
    #pragma unroll
    for (int j = 0; j < 10; ++j) pacc[(q*64 + r)*10 + j] = acc[j];
    __syncthreads();
    if (t < 64){
        float pv[10];
        #pragma unroll
        for (int j = 0; j < 10; ++j){
            float a = ws[B2P_OFF + j];
            a += pacc[t*10+j] + pacc[(64+t)*10+j] + pacc[(128+t)*10+j] + pacc[(192+t)*10+j];
            pv[j] = lrelu(a);
        }
        #pragma unroll
        for (int j = 0; j < 10; ++j) ws[PRAW_OFF + (size_t)(r0 + t)*10 + j] = pv[j];
        float sv[10], qv[10];
        #pragma unroll
        for (int j = 0; j < 10; ++j){ sv[j] = pv[j]; qv[j] = pv[j]*pv[j]; }
        #pragma unroll
        for (int m = 1; m < 64; m <<= 1){
            #pragma unroll
            for (int j = 0; j < 10; ++j){
                sv[j] += __shfl_xor(sv[j], m);
                qv[j] += __shfl_xor(qv[j], m);
            }
        }
        if (t == 0){
            #pragma unroll
            for (int j = 0; j < 10; ++j){
                atomicAdd(&ws[S2_OFF + j], sv[j]);
                atomicAdd(&ws[SQ2_OFF + j], qv[j]);
            }
        }
    }
}

// ---------- batched IPM: 16 lanes per element, 9 constraints per lane ----------
// Register budget per lane (the round-1 fix): persistent z[10]+pv[10]+s[9]+lam[9]=38;
// loop-A adds rp[9]+Hm[55]+lamG[10]+g-temps ~= 145 peak (was ~250+ w/ 18/lane -> spilled).
#define TIX(i,j) ((i)*((i)+1)/2 + (j))
#define LOADG(kk) \
    float4 ga_ = gptr[(kk)*3+0]; float4 gb_ = gptr[(kk)*3+1]; float4 gc_ = gptr[(kk)*3+2]; \
    float g[10] = {ga_.x, ga_.y, ga_.z, ga_.w, gb_.x, gb_.y, gb_.z, gb_.w, gc_.x, gc_.y};

__global__ __launch_bounds__(256) void k_ipm(const float* ws, const float* g2, const float* bb2, float* out){
    __shared__ float sG[144*12];
    __shared__ float sh[144];
    __shared__ float sQm[120];
    __shared__ float sa2[10], sc2[10];
    int t = threadIdx.x;
    for (int i = t; i < 1728; i += 256) sG[i] = ws[G_OFF + i];
    for (int i = t; i < 144; i += 256)  sh[i] = ws[H_OFF + i];
    if (t < 120) sQm[t] = ws[QM_OFF + t];
    if (t < 10){
        float mu  = ws[S2_OFF + t] * (1.0f/16384.0f);
        float var = ws[SQ2_OFF + t] * (1.0f/16384.0f) - mu*mu;
        float a2 = g2[t] / sqrtf(var + BNEPS);
        sa2[t] = a2; sc2[t] = bb2[t] - mu * a2;
    }
    __syncthreads();

    int lg = t & 15;                       // lane within the 16-lane group
    int elem = blockIdx.x * 16 + (t >> 4); // one QP element per group
    int m0 = lg * 9;                       // 16*9 = 144 >= 138 constraints
    const float2* p2 = (const float2*)(ws + PRAW_OFF + (size_t)elem * 10);
    float pv[10];
    #pragma unroll
    for (int i = 0; i < 5; ++i){
        float2 v = p2[i];
        pv[2*i]   = fmaf(v.x, sa2[2*i],   sc2[2*i]);
        pv[2*i+1] = fmaf(v.y, sa2[2*i+1], sc2[2*i+1]);
    }
    float z[10];
    #pragma unroll
    for (int i = 0; i < 10; ++i) z[i] = 0.0f;
    float s[9], lam[9];
    #pragma unroll
    for (int k = 0; k < 9; ++k){ s[k] = 1.0f; lam[k] = (m0 + k < MIx) ? 1.0f : 0.0f; }
    const float4* gptr = (const float4*)(sG + m0 * 12);

    #pragma unroll 1
    for (int it = 0; it < ITERS; ++it){
        float lamG[10], Hm[55], sl = 0.0f, rp[9];
        #pragma unroll
        for (int i = 0; i < 10; ++i) lamG[i] = 0.0f;
        #pragma unroll
        for (int i = 0; i < 55; ++i) Hm[i] = 0.0f;
        // ---- loop A: lam@G, rp, mu partial, H partial
        #pragma unroll
        for (int k = 0; k < 9; ++k){
            LOADG(k);
            float sk = s[k], lk = lam[k];
            #pragma unroll
            for (int i = 0; i < 10; ++i) lamG[i] = fmaf(lk, g[i], lamG[i]);
            float r = sk - sh[m0 + k];
            #pragma unroll
            for (int i = 0; i < 10; ++i) r = fmaf(z[i], g[i], r);
            rp[k] = r;
            sl = fmaf(sk, lk, sl);
            float w = lk * frcp(sk);
            float wg[10];
            #pragma unroll
            for (int i = 0; i < 10; ++i) wg[i] = w * g[i];
            #pragma unroll
            for (int i = 0; i < 10; ++i){
                #pragma unroll
                for (int j = 0; j <= i; ++j) Hm[TIX(i,j)] = fmaf(wg[i], g[j], Hm[TIX(i,j)]);
            }
        }
        // ---- butterfly reductions over the 16-lane group
        #pragma unroll
        for (int m = 1; m < 16; m <<= 1){
            #pragma unroll
            for (int i = 0; i < 10; ++i) lamG[i] += __shfl_xor(lamG[i], m);
            sl += __shfl_xor(sl, m);
            #pragma unroll
            for (int i = 0; i < 55; ++i) Hm[i] += __shfl_xor(Hm[i], m);
        }
        float smu = SIGMA_C * sl * (1.0f/138.0f);
        // rd = z@Qm + p + lam@G
        float rd[10];
        #pragma unroll
        for (int i = 0; i < 10; ++i) rd[i] = pv[i] + lamG[i];
        #pragma unroll
        for (int j = 0; j < 10; ++j){
            float zj = z[j];
            #pragma unroll
            for (int i = 0; i < 10; ++i) rd[i] = fmaf(zj, sQm[j*12 + i], rd[i]);
        }
        // H += Qm
        #pragma unroll
        for (int i = 0; i < 10; ++i){
            #pragma unroll
            for (int j = 0; j <= i; ++j) Hm[TIX(i,j)] += sQm[i*12 + j];
        }
        // ---- loop B: rhs accumulation
        float racc[10];
        #pragma unroll
        for (int i = 0; i < 10; ++i) racc[i] = 0.0f;
        #pragma unroll
        for (int k = 0; k < 9; ++k){
            LOADG(k);
            float sk = s[k], lk = lam[k];
            float isk = frcp(sk);
            float rc = fmaf(sk, lk, -smu);
            float coef = isk * fmaf(lk, rp[k], -rc);
            #pragma unroll
            for (int i = 0; i < 10; ++i) racc[i] = fmaf(coef, g[i], racc[i]);
        }
        #pragma unroll
        for (int m = 1; m < 16; m <<= 1){
            #pragma unroll
            for (int i = 0; i < 10; ++i) racc[i] += __shfl_xor(racc[i], m);
        }
        float rhs[10];
        #pragma unroll
        for (int i = 0; i < 10; ++i) rhs[i] = -(rd[i] + racc[i]);
        // ---- Cholesky (reciprocal diag stored in place)
        #pragma unroll
        for (int j = 0; j < 10; ++j){
            float d = Hm[TIX(j,j)];
            #pragma unroll
            for (int k2 = 0; k2 < j; ++k2){ float v = Hm[TIX(j,k2)]; d = fmaf(-v, v, d); }
            d = fmaxf(d, 1e-30f);
            float rinv = frsq(d);
            Hm[TIX(j,j)] = rinv;
            #pragma unroll
            for (int i = j+1; i < 10; ++i){
                float v2 = Hm[TIX(i,j)];
                #pragma unroll
                for (int k2 = 0; k2 < j; ++k2) v2 = fmaf(-Hm[TIX(i,k2)], Hm[TIX(j,k2)], v2);
                Hm[TIX(i,j)] = v2 * rinv;
            }
        }
        // forward/back solve
        #pragma unroll
        for (int i = 0; i < 10; ++i){
            float v2 = rhs[i];
            #pragma unroll
            for (int k2 = 0; k2 < i; ++k2) v2 = fmaf(-Hm[TIX(i,k2)], rhs[k2], v2);
            rhs[i] = v2 * Hm[TIX(i,i)];
        }
        float dz[10];
        #pragma unroll
        for (int i = 9; i >= 0; --i){
            float v2 = rhs[i];
            #pragma unroll
            for (int k2 = i+1; k2 < 10; ++k2) v2 = fmaf(-Hm[TIX(k2,i)], dz[k2], v2);
            dz[i] = v2 * Hm[TIX(i,i)];
        }
        // ---- loop C: ds, dlam, step-length candidates (low register pressure here)
        float ds[9], dl[9];
        float amin = 3.0e38f;
        #pragma unroll
        for (int k = 0; k < 9; ++k){
            LOADG(k);
            float dot = 0.0f;
            #pragma unroll
            for (int i = 0; i < 10; ++i) dot = fmaf(dz[i], g[i], dot);
            float dsk = -rp[k] - dot;
            bool val = (m0 + k) < MIx;
            dsk = val ? dsk : 0.0f;
            ds[k] = dsk;
            float sk = s[k], lk = lam[k];
            float isk = frcp(sk);
            float rc = fmaf(sk, lk, -smu);
            float dlk = -(rc + lk * dsk) * isk;
            dlk = val ? dlk : 0.0f;
            dl[k] = dlk;
            float r1 = (dsk < 0.0f) ? sk * frcp(-dsk) : 3.0e38f;
            float r2 = (dlk < 0.0f) ? lk * frcp(-dlk) : 3.0e38f;
            amin = fminf(amin, fminf(r1, r2));
        }
        #pragma unroll
        for (int m = 1; m < 16; m <<= 1) amin = fminf(amin, __shfl_xor(amin, m));
        float alpha = fminf(1.0f, 0.99f * amin);
        // ---- updates
        #pragma unroll
        for (int i = 0; i < 10; ++i) z[i] = fmaf(alpha, dz[i], z[i]);
        #pragma unroll
        for (int k = 0; k < 9; ++k){
            s[k]   = fmaf(alpha, ds[k], s[k]);
            lam[k] = fmaf(alpha, dl[k], lam[k]);
        }
    }
    if (lg == 0) out[elem] = z[0];
}

extern "C" void kernel_launch(void* const* d_in, const int* in_sizes, int n_in,
                              void* d_out, int out_size, void* d_ws, size_t ws_size,
                              hipStream_t stream){
    const float* x   = (const float*)d_in[0];
    const float* w1  = (const float*)d_in[1];
    const float* b1  = (const float*)d_in[2];
    const float* w2  = (const float*)d_in[3];
    const float* b2  = (const float*)d_in[4];
    const float* g1  = (const float*)d_in[5];
    const float* bb1 = (const float*)d_in[6];
    const float* g2  = (const float*)d_in[7];
    const float* bb2 = (const float*)d_in[8];
    const float* L   = (const float*)d_in[9];
    const float* LP  = (const float*)d_in[10];
    const float* LR  = (const float*)d_in[11];
    const float* A   = (const float*)d_in[12];
    const float* Bm  = (const float*)d_in[13];
    const float* u0  = (const float*)d_in[14];
    const float* s0  = (const float*)d_in[15];
    float* ws  = (float*)d_ws;
    float* out = (float*)d_out;

    hipLaunchKernelGGL(k_zero,   dim3((ZERO_LEN + 255)/256), dim3(256), 0, stream, ws);
    hipLaunchKernelGGL(k_build,  dim3(1),    dim3(256), 0, stream, L, LP, LR, A, Bm, u0, s0, ws);
    hipLaunchKernelGGL(k_stats1, dim3(256),  dim3(256), 0, stream, x, w1, b1, ws);
    hipLaunchKernelGGL(k_fin1,   dim3(1),    dim3(256), 0, stream, g1, bb1, w2, b2, ws);
    hipLaunchKernelGGL(k_fc2,    dim3(256),  dim3(256), 0, stream, x, w1, b1, w2, ws);
    hipLaunchKernelGGL(k_ipm,    dim3(1024), dim3(256), 0, stream, ws, g2, bb2, out);
}

// Round 3
// 1168.743 us; speedup vs baseline: 4.6433x; 1.6705x over previous
//
#include <hip/hip_runtime.h>
#include <math.h>

#define NIx 32
#define NOx 2
#define NUx 10
#define NHx 1024
#define NBx 16384
#define MIx 138
#define EPSQ 1e-4f
#define BNEPS 1e-5f
#define ITERS 30
#define SLOPE 0.2f
#define SIGMA_C 0.1f

// workspace layout (float offsets)
#define QM_OFF 0       // 10 rows x 12 (padded)
#define G_OFF 128      // 144 rows x 12 (padded, zero pad rows/cols)
#define H_OFF 1856     // 144
#define A1_OFF 2048    // 1024
#define C1_OFF 3072    // 1024
#define B2P_OFF 4096   // 10 (pad to 4112)
#define S1_OFF 4112    // 1024
#define SQ1_OFF 5136   // 1024
#define S2_OFF 6160    // 10 (pad 16)
#define SQ2_OFF 6176   // 10 (pad to 6208)
#define PRAW_OFF 6208  // 16384*10
#define ZERO_LEN (6208 - S1_OFF)

__device__ __forceinline__ float frcp(float x){ return __builtin_amdgcn_rcpf(x); }
__device__ __forceinline__ float frsq(float x){ return __builtin_amdgcn_rsqf(x); }
__device__ __forceinline__ float lrelu(float x){ return x > 0.0f ? x : SLOPE * x; }

__global__ __launch_bounds__(256) void k_zero(float* ws){
    int i = blockIdx.x * 256 + threadIdx.x;
    if (i < ZERO_LEN) ws[S1_OFF + i] = 0.0f;
}

// ---------- build Q_hat, G, h (one block) ----------
__global__ __launch_bounds__(256) void k_build(const float* L, const float* LP, const float* LR,
                                               const float* A, const float* Bm,
                                               const float* u0, const float* s0, float* ws){
    __shared__ float sL[1024], sLP[1024], sA[1024], sQ[1024], sP[1024];
    __shared__ float sPow[4][64];   // [power][i*2+c]
    __shared__ float sBh[128*10];
    __shared__ float sQB[128*10];
    __shared__ float sR[3];
    int t = threadIdx.x;
    for (int idx = t; idx < 1024; idx += 256){
        int i = idx >> 5, j = idx & 31;
        sL[idx]  = (j <= i) ? L[idx]  : 0.0f;
        sLP[idx] = (j <= i) ? LP[idx] : 0.0f;
        sA[idx]  = A[idx];
    }
    if (t < 64) sPow[0][t] = Bm[t];
    if (t == 0){
        float a = LR[0], b = LR[2], c = LR[3];   // tril: [[a,0],[b,c]]
        sR[0] = a*a + EPSQ; sR[1] = a*b; sR[2] = b*b + c*c + EPSQ;
    }
    __syncthreads();
    for (int idx = t; idx < 1024; idx += 256){
        int i = idx >> 5, j = idx & 31;
        float q = 0.0f, p = 0.0f;
        for (int k = 0; k < 32; ++k){
            q = fmaf(sL[i*32+k],  sL[j*32+k],  q);
            p = fmaf(sLP[i*32+k], sLP[j*32+k], p);
        }
        if (i == j){ q += EPSQ; p += EPSQ; }
        sQ[idx] = q; sP[idx] = p;
    }
    for (int kp = 1; kp < 4; ++kp){
        __syncthreads();
        if (t < 64){
            int i = t >> 1, c = t & 1;
            float a = 0.0f;
            for (int j = 0; j < 32; ++j) a = fmaf(sA[i*32+j], sPow[kp-1][j*2+c], a);
            sPow[kp][t] = a;
        }
    }
    __syncthreads();
    for (int idx = t; idx < 1280; idx += 256){
        int r = idx / 10, c = idx % 10;
        int bi = r >> 5, ri = r & 31, bj = c >> 1, cj = c & 1;
        sBh[idx] = (bj <= bi) ? sPow[bi-bj][ri*2+cj] : 0.0f;
    }
    __syncthreads();
    for (int idx = t; idx < 1280; idx += 256){
        int r = idx / 10, c = idx % 10;
        int bi = r >> 5, ri = r & 31;
        const float* Qd = (bi < 3) ? sQ : sP;
        float a = 0.0f;
        for (int k = 0; k < 32; ++k) a = fmaf(Qd[ri*32+k], sBh[(bi*32+k)*10+c], a);
        sQB[idx] = a;
    }
    __syncthreads();
    if (t < 120){
        int i = t / 12, j = t % 12;
        float a = 0.0f;
        if (j < 10){
            for (int r = 0; r < 128; ++r) a = fmaf(sBh[r*10+i], sQB[r*10+j], a);
            if ((i >> 1) == (j >> 1)) a += sR[(i&1)+(j&1)];
        }
        ws[QM_OFF + t] = a;
    }
    for (int idx = t; idx < 144*12; idx += 256){
        int m = idx / 12, i = idx % 12;
        float v = 0.0f;
        if (i < 10 && m < MIx) v = (m < 10) ? ((i == m) ? 1.0f : 0.0f) : sBh[(m-10)*10 + i];
        ws[G_OFF + idx] = v;
    }
    for (int m = t; m < 144; m += 256){
        float hv = 0.0f;
        if (m < MIx){
            hv = s0[m];
            if (m < 10) hv += u0[m];
            else { for (int i = 0; i < 10; ++i) hv = fmaf(sBh[(m-10)*10+i], u0[i], hv); }
        }
        ws[H_OFF + m] = hv;
    }
}

// ---------- BN1 stats: h1 = lrelu(x@W1^T + b1), accumulate per-col sum/sumsq ----------
__global__ __launch_bounds__(256) void k_stats1(const float* x, const float* w1, const float* b1, float* ws){
    __shared__ float xs[256*32];
    int t = threadIdx.x;
    int rb = blockIdx.x >> 2;
    int cb = blockIdx.x & 3;
    int r0 = rb * 256;
    int c = cb * 256 + t;
    const float4* xg4 = (const float4*)(x + (size_t)r0 * 32);
    float4* xs4 = (float4*)xs;
    for (int i = t; i < 2048; i += 256) xs4[i] = xg4[i];
    const float4* wg4 = (const float4*)(w1 + (size_t)c * 32);
    float4 wr[8];
    #pragma unroll
    for (int q = 0; q < 8; ++q) wr[q] = wg4[q];
    float bc = b1[c];
    __syncthreads();
    const float4* xr4 = (const float4*)xs;
    float sum = 0.0f, sq = 0.0f;
    for (int r = 0; r < 256; ++r){
        float a0 = 0, a1 = 0, a2 = 0, a3 = 0;
        #pragma unroll
        for (int q = 0; q < 8; ++q){
            float4 v = xr4[r*8 + q];
            a0 = fmaf(v.x, wr[q].x, a0);
            a1 = fmaf(v.y, wr[q].y, a1);
            a2 = fmaf(v.z, wr[q].z, a2);
            a3 = fmaf(v.w, wr[q].w, a3);
        }
        float h = lrelu((a0 + a1) + (a2 + a3) + bc);
        sum += h; sq = fmaf(h, h, sq);
    }
    atomicAdd(&ws[S1_OFF + c], sum);
    atomicAdd(&ws[SQ1_OFF + c], sq);
}

// ---------- finalize BN1 affine + fold into fc2 bias ----------
__global__ __launch_bounds__(256) void k_fin1(const float* g1, const float* bb1,
                                              const float* w2, const float* b2, float* ws){
    int t = threadIdx.x;
    for (int k = t; k < 1024; k += 256){
        float mu  = ws[S1_OFF + k] * (1.0f/16384.0f);
        float var = ws[SQ1_OFF + k] * (1.0f/16384.0f) - mu*mu;
        float a1 = g1[k] / sqrtf(var + BNEPS);
        ws[A1_OFF + k] = a1;
        ws[C1_OFF + k] = bb1[k] - mu * a1;
    }
    __syncthreads();
    if (t < 10){
        float a = b2[t];
        for (int k = 0; k < 1024; ++k) a = fmaf(ws[C1_OFF + k], w2[t*1024 + k], a);
        ws[B2P_OFF + t] = a;
    }
}

// ---------- fc2: p_raw = lrelu((h1*a1)@W2^T + b2'), + BN2 stats ----------
__global__ __launch_bounds__(256) void k_fc2(const float* x, const float* w1, const float* b1,
                                             const float* w2, float* ws){
    __shared__ float ws1[128*32];     // W1 chunk [kl][c]
    __shared__ float w2t[128*12];     // W2 chunk transposed, padded to 12
    __shared__ float sab[128*2];      // (a1, b1) per kl
    int t = threadIdx.x;
    int r0 = blockIdx.x * 64;
    int r = t & 63;
    int q = t >> 6;                   // wave id: k-quarter
    const float4* xg4 = (const float4*)(x + (size_t)(r0 + r) * 32);
    float4 xr[8];
    #pragma unroll
    for (int i = 0; i < 8; ++i) xr[i] = xg4[i];
    float acc[10];
    #pragma unroll
    for (int j = 0; j < 10; ++j) acc[j] = 0.0f;

    for (int kc = 0; kc < 1024; kc += 128){
        __syncthreads();
        const float4* w1g = (const float4*)(w1 + (size_t)kc * 32);
        float4* ws14 = (float4*)ws1;
        for (int i = t; i < 1024; i += 256) ws14[i] = w1g[i];
        for (int i = t; i < 1280; i += 256){
            int kl = i & 127, j = i >> 7;
            w2t[kl*12 + j] = w2[j*1024 + kc + kl];
        }
        if (t < 256){ int kl = t >> 1, j = 10 + (t & 1); w2t[kl*12 + j] = 0.0f; }
        if (t < 128){ sab[t*2] = ws[A1_OFF + kc + t]; sab[t*2+1] = b1[kc + t]; }
        __syncthreads();
        const float4* w1r = (const float4*)ws1;
        const float4* w2r = (const float4*)w2t;
        const float2* abr = (const float2*)sab;
        #pragma unroll 4
        for (int kk = 0; kk < 32; ++kk){
            int kl = q*32 + kk;
            float a0 = 0, a1 = 0, a2 = 0, a3 = 0;
            #pragma unroll
            for (int qq = 0; qq < 8; ++qq){
                float4 wv = w1r[kl*8 + qq];
                float4 xv = xr[qq];
                a0 = fmaf(xv.x, wv.x, a0);
                a1 = fmaf(xv.y, wv.y, a1);
                a2 = fmaf(xv.z, wv.z, a2);
                a3 = fmaf(xv.w, wv.w, a3);
            }
            float2 ab = abr[kl];
            float h = lrelu((a0 + a1) + (a2 + a3) + ab.y) * ab.x;
            float4 wa = w2r[kl*3+0], wb = w2r[kl*3+1], wc = w2r[kl*3+2];
            acc[0] = fmaf(h, wa.x, acc[0]); acc[1] = fmaf(h, wa.y, acc[1]);
            acc[2] = fmaf(h, wa.z, acc[2]); acc[3] = fmaf(h, wa.w, acc[3]);
            acc[4] = fmaf(h, wb.x, acc[4]); acc[5] = fmaf(h, wb.y, acc[5]);
            acc[6] = fmaf(h, wb.z, acc[6]); acc[7] = fmaf(h, wb.w, acc[7]);
            acc[8] = fmaf(h, wc.x, acc[8]); acc[9] = fmaf(h, wc.y, acc[9]);
        }
    }
    __syncthreads();
    float* pacc = ws1;   // reuse LDS
    #pragma unroll
    for (int j = 0; j < 10; ++j) pacc[(q*64 + r)*10 + j] = acc[j];
    __syncthreads();
    if (t < 64){
        float pv[10];
        #pragma unroll
        for (int j = 0; j < 10; ++j){
            float a = ws[B2P_OFF + j];
            a += pacc[t*10+j] + pacc[(64+t)*10+j] + pacc[(128+t)*10+j] + pacc[(192+t)*10+j];
            pv[j] = lrelu(a);
        }
        #pragma unroll
        for (int j = 0; j < 10; ++j) ws[PRAW_OFF + (size_t)(r0 + t)*10 + j] = pv[j];
        float sv[10], qv[10];
        #pragma unroll
        for (int j = 0; j < 10; ++j){ sv[j] = pv[j]; qv[j] = pv[j]*pv[j]; }
        #pragma unroll
        for (int m = 1; m < 64; m <<= 1){
            #pragma unroll
            for (int j = 0; j < 10; ++j){
                sv[j] += __shfl_xor(sv[j], m);
                qv[j] += __shfl_xor(qv[j], m);
            }
        }
        if (t == 0){
            #pragma unroll
            for (int j = 0; j < 10; ++j){
                atomicAdd(&ws[S2_OFF + j], sv[j]);
                atomicAdd(&ws[SQ2_OFF + j], qv[j]);
            }
        }
    }
}

// ---------- batched IPM, sparsity-aware ----------
// 16 lanes/element. Constraint -> (lane,slot) mapping (permutation-invariant QP):
//   slot k=0..7: B_hat block b=k/2, row = b*32 + (k&1)*16 + lane; column bound 2(b+1) (compile-time!)
//   slot k=8   : identity row `lane` (lanes 0..9), g = e_lane handled analytically.
// G held in registers (40 floats, sparsity-packed), loaded once -> no per-iter G traffic,
// H accumulation only touches tri(8)=36 entries (B_hat cols 8,9 are zero) -> butterfly 45 vals.
#define TIX(i,j) ((i)*((i)+1)/2 + (j))

#define STEPA(K, B, g) { \
    float sk = s[K], lk = lam[K]; \
    float r = sk - hh[K]; \
    float w = lk * frcp(sk); \
    sl = fmaf(sk, lk, sl); \
    _Pragma("unroll") \
    for (int i = 0; i < B; ++i){ \
        lamG[i] = fmaf(lk, g[i], lamG[i]); \
        r = fmaf(z[i], g[i], r); \
    } \
    rp[K] = r; \
    _Pragma("unroll") \
    for (int i = 0; i < B; ++i){ \
        float wgi = w * g[i]; \
        _Pragma("unroll") \
        for (int j = 0; j <= i; ++j) Hm[TIX(i,j)] = fmaf(wgi, g[j], Hm[TIX(i,j)]); \
    } }

#define STEPB(K, B, g) { \
    float sk = s[K], lk = lam[K]; \
    float isk = frcp(sk); \
    float rc = fmaf(sk, lk, -smu); \
    float coef = isk * fmaf(lk, rp[K], -rc); \
    _Pragma("unroll") \
    for (int i = 0; i < B; ++i) racc[i] = fmaf(coef, g[i], racc[i]); }

#define STEPC(K, B, g) { \
    float dot = 0.0f; \
    _Pragma("unroll") \
    for (int i = 0; i < B; ++i) dot = fmaf(dz[i], g[i], dot); \
    float dsk = -rp[K] - dot; \
    float sk = s[K], lk = lam[K]; \
    float isk = frcp(sk); \
    float rc = fmaf(sk, lk, -smu); \
    float dlk = -(rc + lk * dsk) * isk; \
    ds_[K] = dsk; dl_[K] = dlk; \
    float r1 = (dsk < 0.0f) ? sk * frcp(-dsk) : 3.0e38f; \
    float r2 = (dlk < 0.0f) ? lk * frcp(-dlk) : 3.0e38f; \
    amin = fminf(amin, fminf(r1, r2)); }

#define LDG(g, c, B) { _Pragma("unroll") for (int i = 0; i < B; ++i) g[i] = GB[(c)*12 + i]; }

__global__ __launch_bounds__(256) void k_ipm(const float* ws, const float* g2, const float* bb2, float* out){
    __shared__ __align__(16) float sQm[120];
    __shared__ float sa2[10], sc2[10];
    int t = threadIdx.x;
    if (t < 120) sQm[t] = ws[QM_OFF + t];
    if (t < 10){
        float mu  = ws[S2_OFF + t] * (1.0f/16384.0f);
        float var = ws[SQ2_OFF + t] * (1.0f/16384.0f) - mu*mu;
        float a2 = g2[t] / sqrtf(var + BNEPS);
        sa2[t] = a2; sc2[t] = bb2[t] - mu * a2;
    }
    __syncthreads();

    int lg = t & 15;
    int elem = blockIdx.x * 16 + (t >> 4);
    const float* GB = ws + G_OFF;
    const float* HB = ws + H_OFF;

    // --- persistent per-lane G rows (sparsity-packed) + h ---
    float g0[2], g1[2], g2r[4], g3[4], g4[6], g5[6], g6[8], g7[8];
    float hh[8];
    {
        int c = 10 + lg;            LDG(g0, c, 2);  hh[0] = HB[c];
        c = 10 + 16 + lg;           LDG(g1, c, 2);  hh[1] = HB[c];
        c = 10 + 32 + lg;           LDG(g2r, c, 4); hh[2] = HB[c];
        c = 10 + 48 + lg;           LDG(g3, c, 4);  hh[3] = HB[c];
        c = 10 + 64 + lg;           LDG(g4, c, 6);  hh[4] = HB[c];
        c = 10 + 80 + lg;           LDG(g5, c, 6);  hh[5] = HB[c];
        c = 10 + 96 + lg;           LDG(g6, c, 8);  hh[6] = HB[c];
        c = 10 + 112 + lg;          LDG(g7, c, 8);  hh[7] = HB[c];
    }
    float h8 = HB[lg & 7];                       // safe read; fixed below
    h8 = (lg < 10) ? HB[lg] : 1.0f;

    // p with BN2 folded
    const float2* p2 = (const float2*)(ws + PRAW_OFF + (size_t)elem * 10);
    float pv[10];
    #pragma unroll
    for (int i = 0; i < 5; ++i){
        float2 v = p2[i];
        pv[2*i]   = fmaf(v.x, sa2[2*i],   sc2[2*i]);
        pv[2*i+1] = fmaf(v.y, sa2[2*i+1], sc2[2*i+1]);
    }
    float z[10];
    #pragma unroll
    for (int i = 0; i < 10; ++i) z[i] = 0.0f;
    float s[9], lam[9], rp[9];
    #pragma unroll
    for (int k = 0; k < 9; ++k){ s[k] = 1.0f; lam[k] = 1.0f; }
    lam[8] = (lg < 10) ? 1.0f : 0.0f;
    const float4* sQm4 = (const float4*)sQm;

    #pragma unroll 1
    for (int it = 0; it < ITERS; ++it){
        float lamG[8], Hm[55], sl = 0.0f;
        #pragma unroll
        for (int i = 0; i < 8; ++i) lamG[i] = 0.0f;
        #pragma unroll
        for (int i = 0; i < 55; ++i) Hm[i] = 0.0f;
        // ---- loop A (B_hat rows, compile-time bounds)
        STEPA(0, 2, g0)  STEPA(1, 2, g1)
        STEPA(2, 4, g2r) STEPA(3, 4, g3)
        STEPA(4, 6, g4)  STEPA(5, 6, g5)
        STEPA(6, 8, g6)  STEPA(7, 8, g7)
        // ---- identity row (slot 8)
        float zs = z[0];
        #pragma unroll
        for (int i = 1; i < 10; ++i) zs = (lg == i) ? z[i] : zs;
        float w8;
        {
            float sk = s[8], lk = lam[8];
            rp[8] = zs + sk - h8;
            sl = fmaf(sk, lk, sl);
            w8 = lk * frcp(sk);
        }
        // ---- butterfly: Hm[0..35], lamG[0..7], sl
        #pragma unroll
        for (int m = 1; m < 16; m <<= 1){
            #pragma unroll
            for (int i = 0; i < 36; ++i) Hm[i] += __shfl_xor(Hm[i], m);
            #pragma unroll
            for (int i = 0; i < 8; ++i) lamG[i] += __shfl_xor(lamG[i], m);
            sl += __shfl_xor(sl, m);
        }
        float smu = SIGMA_C * sl * (1.0f/138.0f);
        // ---- identity contributions (broadcast from lanes 0..9)
        float lamG8 = __shfl(lam[8], 8, 16);
        float lamG9 = __shfl(lam[8], 9, 16);
        #pragma unroll
        for (int m = 0; m < 8; ++m) lamG[m] += __shfl(lam[8], m, 16);
        #pragma unroll
        for (int m = 0; m < 8; ++m) Hm[TIX(m,m)] += __shfl(w8, m, 16);
        float Hd8 = __shfl(w8, 8, 16);
        float Hd9 = __shfl(w8, 9, 16);
        // ---- rd = p + lamG + Qz, and H += Q (one pass over Q rows)
        float rd[10];
        #pragma unroll
        for (int i = 0; i < 8; ++i) rd[i] = pv[i] + lamG[i];
        rd[8] = pv[8] + lamG8; rd[9] = pv[9] + lamG9;
        #pragma unroll
        for (int j = 0; j < 10; ++j){
            float4 qa = sQm4[j*3+0], qb = sQm4[j*3+1], qc = sQm4[j*3+2];
            float q[10] = {qa.x,qa.y,qa.z,qa.w, qb.x,qb.y,qb.z,qb.w, qc.x,qc.y};
            float zj = z[j];
            #pragma unroll
            for (int i = 0; i < 10; ++i) rd[i] = fmaf(zj, q[i], rd[i]);
            #pragma unroll
            for (int i = 0; i <= j; ++i) Hm[TIX(j,i)] += q[i];
        }
        Hm[TIX(8,8)] += Hd8;
        Hm[TIX(9,9)] += Hd9;
        // ---- loop B: rhs
        float racc[8];
        #pragma unroll
        for (int i = 0; i < 8; ++i) racc[i] = 0.0f;
        STEPB(0, 2, g0)  STEPB(1, 2, g1)
        STEPB(2, 4, g2r) STEPB(3, 4, g3)
        STEPB(4, 6, g4)  STEPB(5, 6, g5)
        STEPB(6, 8, g6)  STEPB(7, 8, g7)
        float coef8;
        {
            float sk = s[8], lk = lam[8];
            float isk = frcp(sk);
            float rc = fmaf(sk, lk, -smu);
            coef8 = isk * fmaf(lk, rp[8], -rc);
            coef8 = (lg < 10) ? coef8 : 0.0f;
        }
        #pragma unroll
        for (int m = 1; m < 16; m <<= 1){
            #pragma unroll
            for (int i = 0; i < 8; ++i) racc[i] += __shfl_xor(racc[i], m);
        }
        float rhs[10];
        #pragma unroll
        for (int m = 0; m < 8; ++m) racc[m] += __shfl(coef8, m, 16);
        float racc8 = __shfl(coef8, 8, 16);
        float racc9 = __shfl(coef8, 9, 16);
        #pragma unroll
        for (int i = 0; i < 8; ++i) rhs[i] = -(rd[i] + racc[i]);
        rhs[8] = -(rd[8] + racc8); rhs[9] = -(rd[9] + racc9);
        // ---- Cholesky (reciprocal diag in place)
        #pragma unroll
        for (int j = 0; j < 10; ++j){
            float d = Hm[TIX(j,j)];
            #pragma unroll
            for (int k2 = 0; k2 < j; ++k2){ float v = Hm[TIX(j,k2)]; d = fmaf(-v, v, d); }
            d = fmaxf(d, 1e-30f);
            float rinv = frsq(d);
            Hm[TIX(j,j)] = rinv;
            #pragma unroll
            for (int i = j+1; i < 10; ++i){
                float v2 = Hm[TIX(i,j)];
                #pragma unroll
                for (int k2 = 0; k2 < j; ++k2) v2 = fmaf(-Hm[TIX(i,k2)], Hm[TIX(j,k2)], v2);
                Hm[TIX(i,j)] = v2 * rinv;
            }
        }
        #pragma unroll
        for (int i = 0; i < 10; ++i){
            float v2 = rhs[i];
            #pragma unroll
            for (int k2 = 0; k2 < i; ++k2) v2 = fmaf(-Hm[TIX(i,k2)], rhs[k2], v2);
            rhs[i] = v2 * Hm[TIX(i,i)];
        }
        float dz[10];
        #pragma unroll
        for (int i = 9; i >= 0; --i){
            float v2 = rhs[i];
            #pragma unroll
            for (int k2 = i+1; k2 < 10; ++k2) v2 = fmaf(-Hm[TIX(k2,i)], dz[k2], v2);
            dz[i] = v2 * Hm[TIX(i,i)];
        }
        // ---- loop C: steps + alpha
        float ds_[9], dl_[9];
        float amin = 3.0e38f;
        STEPC(0, 2, g0)  STEPC(1, 2, g1)
        STEPC(2, 4, g2r) STEPC(3, 4, g3)
        STEPC(4, 6, g4)  STEPC(5, 6, g5)
        STEPC(6, 8, g6)  STEPC(7, 8, g7)
        {
            float dzs = dz[0];
            #pragma unroll
            for (int i = 1; i < 10; ++i) dzs = (lg == i) ? dz[i] : dzs;
            float dsk = -rp[8] - dzs;
            bool val = lg < 10;
            dsk = val ? dsk : 0.0f;
            float sk = s[8], lk = lam[8];
            float isk = frcp(sk);
            float rc = fmaf(sk, lk, -smu);
            float dlk = -(rc + lk * dsk) * isk;
            dlk = val ? dlk : 0.0f;
            ds_[8] = dsk; dl_[8] = dlk;
            float r1 = (dsk < 0.0f) ? sk * frcp(-dsk) : 3.0e38f;
            float r2 = (dlk < 0.0f) ? lk * frcp(-dlk) : 3.0e38f;
            amin = fminf(amin, fminf(r1, r2));
        }
        #pragma unroll
        for (int m = 1; m < 16; m <<= 1) amin = fminf(amin, __shfl_xor(amin, m));
        float alpha = fminf(1.0f, 0.99f * amin);
        // ---- updates
        #pragma unroll
        for (int i = 0; i < 10; ++i) z[i] = fmaf(alpha, dz[i], z[i]);
        #pragma unroll
        for (int k = 0; k < 9; ++k){
            s[k]   = fmaf(alpha, ds_[k], s[k]);
            lam[k] = fmaf(alpha, dl_[k], lam[k]);
        }
    }
    if (lg == 0) out[elem] = z[0];
}

extern "C" void kernel_launch(void* const* d_in, const int* in_sizes, int n_in,
                              void* d_out, int out_size, void* d_ws, size_t ws_size,
                              hipStream_t stream){
    const float* x   = (const float*)d_in[0];
    const float* w1  = (const float*)d_in[1];
    const float* b1  = (const float*)d_in[2];
    const float* w2  = (const float*)d_in[3];
    const float* b2  = (const float*)d_in[4];
    const float* g1  = (const float*)d_in[5];
    const float* bb1 = (const float*)d_in[6];
    const float* g2  = (const float*)d_in[7];
    const float* bb2 = (const float*)d_in[8];
    const float* L   = (const float*)d_in[9];
    const float* LP  = (const float*)d_in[10];
    const float* LR  = (const float*)d_in[11];
    const float* A   = (const float*)d_in[12];
    const float* Bm  = (const float*)d_in[13];
    const float* u0  = (const float*)d_in[14];
    const float* s0  = (const float*)d_in[15];
    float* ws  = (float*)d_ws;
    float* out = (float*)d_out;

    hipLaunchKernelGGL(k_zero,   dim3((ZERO_LEN + 255)/256), dim3(256), 0, stream, ws);
    hipLaunchKernelGGL(k_build,  dim3(1),    dim3(256), 0, stream, L, LP, LR, A, Bm, u0, s0, ws);
    hipLaunchKernelGGL(k_stats1, dim3(256),  dim3(256), 0, stream, x, w1, b1, ws);
    hipLaunchKernelGGL(k_fin1,   dim3(1),    dim3(256), 0, stream, g1, bb1, w2, b2, ws);
    hipLaunchKernelGGL(k_fc2,    dim3(256),  dim3(256), 0, stream, x, w1, b1, w2, ws);
    hipLaunchKernelGGL(k_ipm,    dim3(1024), dim3(256), 0, stream, ws, g2, bb2, out);
}